// Round 1
// baseline (91.104 us; speedup 1.0000x reference)
//
#include <hip/hip_runtime.h>

// Problem constants (match reference)
#define BATCH 32
#define HW    3136   // 56*56
#define NCH   256
// pixels total = BATCH*HW = 100352
// main grid = 100352/4 = 25088 blocks of 256 threads (4 pixels/block, 1 wave/pixel)

// ---------------------------------------------------------------------------
// Pre-pass: transpose perm [C, HW] -> permT [HW, C] with mask fused:
//   permT[p*C + ch] = (mask[ch] != 0) ? perm[ch*HW + p] : p
// LDS 32x32 tile transpose, coalesced on both sides.
// grid = (HW/32) * (C/32) = 98 * 8 = 784 blocks, 256 threads (32x8)
// ---------------------------------------------------------------------------
__global__ __launch_bounds__(256) void transpose_perm_kernel(
    const int* __restrict__ perm, const float* __restrict__ mask,
    int* __restrict__ permT) {
  __shared__ int tile[32][33];  // +1 pad: conflict-free transpose
  const int tx = threadIdx.x & 31;
  const int ty = threadIdx.x >> 5;  // 0..7
  const int p0 = (blockIdx.x % 98) * 32;
  const int c0 = (blockIdx.x / 98) * 32;

#pragma unroll
  for (int j = 0; j < 4; ++j) {
    const int ch = c0 + ty + 8 * j;
    tile[ty + 8 * j][tx] = perm[ch * HW + p0 + tx];  // coalesced along p
  }
  __syncthreads();
#pragma unroll
  for (int j = 0; j < 4; ++j) {
    const int p = p0 + ty + 8 * j;
    const int ch = c0 + tx;
    const int v = tile[tx][ty + 8 * j];
    permT[p * NCH + ch] = (mask[ch] != 0.0f) ? v : p;  // coalesced along ch
  }
}

// ---------------------------------------------------------------------------
// Main gather: one wave per pixel (b,p); lane handles 4 consecutive channels.
//   index read: int4 coalesced (1KB/wave)
//   gather read: 4x scattered 4B loads within the 3.21MB batch slab (L2-able)
//   out write: float4 coalesced (1KB/wave)
// XCD-aware bijective swizzle: grid 25088 = 8*3136, so XCD k gets batches
// 4k..4k+3 contiguously -> per-XCD L2 (4MiB) holds the active batch slab.
// ---------------------------------------------------------------------------
__global__ __launch_bounds__(256) void jumble_kernel(
    const float* __restrict__ x, const int* __restrict__ permT,
    float* __restrict__ out) {
  const unsigned bid = blockIdx.x;
  const unsigned nbid = (bid & 7u) * 3136u + (bid >> 3);  // bijective XCD swizzle
  const unsigned pix = nbid * 4u + (threadIdx.x >> 6);    // global pixel
  const unsigned lane = threadIdx.x & 63u;

  const unsigned b = pix / HW;
  const unsigned p = pix - b * HW;

  const int4 rows = ((const int4*)permT)[p * (NCH / 4) + lane];

  const float* __restrict__ xb = x + (size_t)b * (HW * NCH);
  const int ch = (int)lane * 4;

  float4 v;
  v.x = xb[rows.x * NCH + ch + 0];
  v.y = xb[rows.y * NCH + ch + 1];
  v.z = xb[rows.z * NCH + ch + 2];
  v.w = xb[rows.w * NCH + ch + 3];

  ((float4*)out)[(size_t)pix * (NCH / 4) + lane] = v;
}

// ---------------------------------------------------------------------------
// Fallback (no workspace): read perm directly (stride-HW scattered, L2/L3
// cached thanks to 32x cross-batch reuse). One thread per element.
// ---------------------------------------------------------------------------
__global__ __launch_bounds__(256) void jumble_direct_kernel(
    const float* __restrict__ x, const float* __restrict__ mask,
    const int* __restrict__ perm, float* __restrict__ out) {
  const int idx = blockIdx.x * 256 + threadIdx.x;  // element id, ch fastest
  const int ch = idx & (NCH - 1);
  const int pix = idx >> 8;
  const int b = pix / HW;
  const int p = pix - b * HW;
  const int row = (mask[ch] != 0.0f) ? perm[ch * HW + p] : p;
  out[idx] = x[(b * HW + row) * NCH + ch];
}

extern "C" void kernel_launch(void* const* d_in, const int* in_sizes, int n_in,
                              void* d_out, int out_size, void* d_ws, size_t ws_size,
                              hipStream_t stream) {
  const float* x = (const float*)d_in[0];
  const float* mask = (const float*)d_in[1];
  const int* perm = (const int*)d_in[2];
  float* out = (float*)d_out;

  const size_t permT_bytes = (size_t)HW * NCH * sizeof(int);  // 3,211,264 B

  if (ws_size >= permT_bytes) {
    int* permT = (int*)d_ws;
    transpose_perm_kernel<<<784, 256, 0, stream>>>(perm, mask, permT);
    jumble_kernel<<<25088, 256, 0, stream>>>(x, permT, out);
  } else {
    jumble_direct_kernel<<<(BATCH * HW * NCH) / 256, 256, 0, stream>>>(
        x, mask, perm, out);
  }
}

// Round 2
// 49.261 us; speedup vs baseline: 1.8494x; 1.8494x over previous
//
#include <hip/hip_runtime.h>

// Problem constants (match reference)
#define BATCH 32
#define HW    3136   // 56*56  (3136 % 32 == 0 -> channel-major LDS is conflict-free)
#define NCH   256
#define CHB   8      // channels per block: HW*CHB*4 = 100,352 B LDS
#define THREADS 1024

// ---------------------------------------------------------------------------
// LDS-staged per-channel spatial jumble.
//   out[b,p,ch] = mask[ch] ? x[b, perm[ch,p], ch] : x[b,p,ch]
// The per-channel permutation spans all HW rows, so the irreducible scatter
// is moved into LDS: stage x[b, :, ch0..ch0+7] (100 KB), then gather from LDS.
// Global side is fully coalesced in both directions.
//
// LDS layout is CHANNEL-MAJOR: lds[c*HW + p]. Since HW % 32 == 0, the bank of
// element (c, r) is r % 32 -> random perm rows spread uniformly over banks
// (~2-way on gather reads = free); staging writes are exactly 2-way (free).
//
// Grid 1024 = 32 b x 32 chblk. XCD remap: xcd k owns batches 4k..4k+3,
// channel-block-major, so x lines shared by adjacent channel blocks and the
// re-read perm slices stay in the local 4 MiB L2.
// ---------------------------------------------------------------------------
__global__ __launch_bounds__(THREADS) void jumble_staged_kernel(
    const float* __restrict__ x, const float* __restrict__ mask,
    const int* __restrict__ perm, float* __restrict__ out) {
  __shared__ float lds[HW * CHB];  // 100,352 B

  const unsigned hw_bid = blockIdx.x;
  const unsigned xcd = hw_bid & 7u;
  const unsigned l = hw_bid >> 3;          // 0..127 within xcd
  const unsigned chblk = l >> 2;           // 0..31  (chblk-major within xcd)
  const unsigned b = 4u * xcd + (l & 3u);  // 4 batches per xcd
  const unsigned ch0 = chblk * CHB;

  const unsigned t = threadIdx.x;

  // ---- stage x[b, :, ch0..ch0+7] into LDS (coalesced float4 reads) ----
  const float4* __restrict__ xg4 = (const float4*)(x + (size_t)b * (HW * NCH));
  for (unsigned f = t; f < HW * CHB / 4; f += THREADS) {
    const unsigned p = f >> 1, cq = f & 1u;  // cq: which half of the 8 channels
    const float4 v = xg4[p * (NCH / 4) + (ch0 / 4) + cq];
    const unsigned cb = cq * 4u;
    lds[(cb + 0) * HW + p] = v.x;  // banks = p%32 -> 2-way, free
    lds[(cb + 1) * HW + p] = v.y;
    lds[(cb + 2) * HW + p] = v.z;
    lds[(cb + 3) * HW + p] = v.w;
  }

  // per-thread fixed channel pair (loop stride 1024 keeps cp invariant)
  const unsigned cp = t & 3u;      // 0..3
  const unsigned c0l = 2u * cp;    // local channel: 0,2,4,6
  const int* __restrict__ permA = perm + (size_t)(ch0 + c0l) * HW;
  const int* __restrict__ permB = perm + (size_t)(ch0 + c0l + 1) * HW;
  const bool m0 = mask[ch0 + c0l] != 0.0f;
  const bool m1 = mask[ch0 + c0l + 1] != 0.0f;

  __syncthreads();

  // ---- gather from LDS, coalesced float2 writes + 64B-segment perm reads ----
  float2* __restrict__ og2 = (float2*)(out + (size_t)b * (HW * NCH) + ch0);
  for (unsigned f = t; f < HW * CHB / 2; f += THREADS) {
    const unsigned p = f >> 2;  // 4 channel-pairs per pixel
    const int r0 = m0 ? permA[p] : (int)p;
    const int r1 = m1 ? permB[p] : (int)p;
    float2 v;
    v.x = lds[(c0l + 0) * HW + r0];  // banks = r%32 -> ~uniform random, ~2-way
    v.y = lds[(c0l + 1) * HW + r1];
    og2[p * (NCH / 2) + cp] = v;
  }
}

extern "C" void kernel_launch(void* const* d_in, const int* in_sizes, int n_in,
                              void* d_out, int out_size, void* d_ws, size_t ws_size,
                              hipStream_t stream) {
  const float* x = (const float*)d_in[0];
  const float* mask = (const float*)d_in[1];
  const int* perm = (const int*)d_in[2];
  float* out = (float*)d_out;

  jumble_staged_kernel<<<BATCH * (NCH / CHB), THREADS, 0, stream>>>(
      x, mask, perm, out);
}